// Round 2
// baseline (396.313 us; speedup 1.0000x reference)
//
#include <hip/hip_runtime.h>
#include <hip/hip_cooperative_groups.h>
#include <math.h>

namespace cg = cooperative_groups;

// Problem constants (match reference)
#define BATCH 8192
#define DIM   1024
#define GRP   8
#define NBLK  1024                        // cooperative grid: 1024 blocks x 256 thr
#define NPART 256                         // partials for fallback path
constexpr float EPS   = 1e-12f;
constexpr float INV_N = 1.0f / (float(BATCH) * float(DIM)); // 1 / 8388608

__device__ __forceinline__ float4 relu_sub(float4 v, float m) {
    v.x = fmaxf(v.x - m, 0.0f);
    v.y = fmaxf(v.y - m, 0.0f);
    v.z = fmaxf(v.z - m, 0.0f);
    v.w = fmaxf(v.w - m, 0.0f);
    return v;
}
__device__ __forceinline__ float sum4(float4 v) {
    return (v.x + v.y) + (v.z + v.w);
}
__device__ __forceinline__ float ssq4(float4 v) {
    return (v.x * v.x + v.y * v.y) + (v.z * v.z + v.w * v.w);
}
__device__ __forceinline__ float4 mul4(float4 v, float s) {
    v.x *= s; v.y *= s; v.z *= s; v.w *= s;
    return v;
}

// ---------------------------------------------------------------------------
// Fused cooperative kernel: 1024 blocks x 256 threads = 4096 waves,
// 2 rows per wave. xf is read from HBM exactly once (lives in registers
// across the grid sync). 4 blocks/CU co-resident (<=128 VGPR needed; we use
// ~64), so the cooperative launch requirement is met with wide margin.
//
// Phase 1: load both rows -> regs, block partial sum -> ws[blockIdx.x]
//          (all 1024 slots overwritten, no zero-init of ws needed)
// grid.sync()
// Phase 2: every block reduces the 1024 partials (1 float4/thread) -> mean
// Phase 3: relu(x-mean), per-row ssq butterfly, scale, 8 tiled float4 stores
// ---------------------------------------------------------------------------
__global__ __launch_bounds__(256, 4)
void fused_kernel(const float* __restrict__ xf,
                  const float* __restrict__ wp,
                  float* __restrict__ ws,
                  float* __restrict__ out) {
    const int tid  = threadIdx.x;                      // 0..255
    const int lane = tid & 63;
    const int wave = tid >> 6;                         // 0..3
    const int row0 = blockIdx.x * 8 + wave * 2;        // 2 consecutive rows/wave
    const int row1 = row0 + 1;

    // ---- Phase 1: load rows into registers, global partial sum ----
    const float4* xa = reinterpret_cast<const float4*>(xf + (size_t)row0 * DIM);
    const float4* xb = reinterpret_cast<const float4*>(xf + (size_t)row1 * DIM);
    float4 a0 = xa[lane], a1 = xa[lane + 64], a2 = xa[lane + 128], a3 = xa[lane + 192];
    float4 b0 = xb[lane], b1 = xb[lane + 64], b2 = xb[lane + 128], b3 = xb[lane + 192];

    float s = (sum4(a0) + sum4(a1)) + (sum4(a2) + sum4(a3))
            + (sum4(b0) + sum4(b1)) + (sum4(b2) + sum4(b3));
    #pragma unroll
    for (int off = 32; off > 0; off >>= 1)
        s += __shfl_down(s, off, 64);

    __shared__ float sm[4];
    if (lane == 0) sm[wave] = s;
    __syncthreads();
    if (tid == 0) ws[blockIdx.x] = (sm[0] + sm[1]) + (sm[2] + sm[3]);

    // ---- all 1024 partials visible to all blocks ----
    cg::this_grid().sync();

    // ---- Phase 2: reduce 1024 partials -> mean (in every thread) ----
    const float4* w4 = reinterpret_cast<const float4*>(ws);
    float p = sum4(w4[tid]);                           // 256 thr x 4 = 1024
    #pragma unroll
    for (int off = 32; off > 0; off >>= 1)
        p += __shfl_xor(p, off, 64);
    if (lane == 0) sm[wave] = p;                       // safe: grid sync above
    __syncthreads();
    const float mean = ((sm[0] + sm[1]) + (sm[2] + sm[3])) * INV_N;

    // ---- Phase 3: relu, per-row L2 norm, scale, tiled stores ----
    a0 = relu_sub(a0, mean); a1 = relu_sub(a1, mean);
    a2 = relu_sub(a2, mean); a3 = relu_sub(a3, mean);
    b0 = relu_sub(b0, mean); b1 = relu_sub(b1, mean);
    b2 = relu_sub(b2, mean); b3 = relu_sub(b3, mean);

    float sa = (ssq4(a0) + ssq4(a1)) + (ssq4(a2) + ssq4(a3));
    float sb = (ssq4(b0) + ssq4(b1)) + (ssq4(b2) + ssq4(b3));
    #pragma unroll
    for (int off = 32; off > 0; off >>= 1) {
        sa += __shfl_xor(sa, off, 64);
        sb += __shfl_xor(sb, off, 64);
    }

    const float sig    = 1.0f / (1.0f + expf(-wp[0]));
    const float scalea = sig / fmaxf(sqrtf(sa), EPS);
    const float scaleb = sig / fmaxf(sqrtf(sb), EPS);

    a0 = mul4(a0, scalea); a1 = mul4(a1, scalea);
    a2 = mul4(a2, scalea); a3 = mul4(a3, scalea);
    b0 = mul4(b0, scaleb); b1 = mul4(b1, scaleb);
    b2 = mul4(b2, scaleb); b3 = mul4(b3, scaleb);

    float4* oa = reinterpret_cast<float4*>(out + (size_t)row0 * (GRP * DIM));
    float4* ob = reinterpret_cast<float4*>(out + (size_t)row1 * (GRP * DIM));
    #pragma unroll
    for (int g = 0; g < GRP; ++g) {
        const int base = g * (DIM / 4);
        oa[base + lane]       = a0;
        oa[base + lane + 64]  = a1;
        oa[base + lane + 128] = a2;
        oa[base + lane + 192] = a3;
        ob[base + lane]       = b0;
        ob[base + lane + 64]  = b1;
        ob[base + lane + 128] = b2;
        ob[base + lane + 192] = b3;
    }
}

// ---------------------------------------------------------------------------
// Fallback path (two kernels), used only if the cooperative launch is refused.
// ---------------------------------------------------------------------------
__global__ __launch_bounds__(1024)
void partial_sum_kernel(const float* __restrict__ xf,
                        float* __restrict__ ws) {
    const int tid = threadIdx.x;
    const int gid = blockIdx.x * 1024 + tid;
    const float4* x4 = reinterpret_cast<const float4*>(xf);
    float s = 0.0f;
    #pragma unroll
    for (int i = 0; i < 8; ++i) {
        float4 v = x4[gid + i * 262144];
        s += sum4(v);
    }
    #pragma unroll
    for (int off = 32; off > 0; off >>= 1)
        s += __shfl_down(s, off, 64);
    __shared__ float sm[16];
    const int lane = tid & 63;
    const int wave = tid >> 6;
    if (lane == 0) sm[wave] = s;
    __syncthreads();
    if (tid == 0) {
        float t = 0.0f;
        #pragma unroll
        for (int w = 0; w < 16; ++w) t += sm[w];
        ws[blockIdx.x] = t;
    }
}

__global__ __launch_bounds__(256)
void norm_tile_kernel(const float* __restrict__ xf,
                      const float* __restrict__ wp,
                      const float* __restrict__ ws,
                      float* __restrict__ out) {
    const int tid  = threadIdx.x;
    const int lane = tid & 63;
    const int row  = (blockIdx.x << 2) | (tid >> 6);

    const float4* xr = reinterpret_cast<const float4*>(xf + (size_t)row * DIM);
    float4 v0 = xr[lane];
    float4 v1 = xr[lane + 64];
    float4 v2 = xr[lane + 128];
    float4 v3 = xr[lane + 192];

    float p = (ws[lane] + ws[lane + 64]) + (ws[lane + 128] + ws[lane + 192]);
    #pragma unroll
    for (int off = 32; off > 0; off >>= 1)
        p += __shfl_xor(p, off, 64);
    const float mean = p * INV_N;

    v0 = relu_sub(v0, mean); v1 = relu_sub(v1, mean);
    v2 = relu_sub(v2, mean); v3 = relu_sub(v3, mean);

    float s = (ssq4(v0) + ssq4(v1)) + (ssq4(v2) + ssq4(v3));
    #pragma unroll
    for (int off = 32; off > 0; off >>= 1)
        s += __shfl_xor(s, off, 64);

    const float sig   = 1.0f / (1.0f + expf(-wp[0]));
    const float scale = sig / fmaxf(sqrtf(s), EPS);

    v0 = mul4(v0, scale); v1 = mul4(v1, scale);
    v2 = mul4(v2, scale); v3 = mul4(v3, scale);

    float4* orow = reinterpret_cast<float4*>(out + (size_t)row * (GRP * DIM));
    #pragma unroll
    for (int g = 0; g < GRP; ++g) {
        const int b = g * (DIM / 4);
        orow[b + lane]       = v0;
        orow[b + lane + 64]  = v1;
        orow[b + lane + 128] = v2;
        orow[b + lane + 192] = v3;
    }
}

// ---------------------------------------------------------------------------
extern "C" void kernel_launch(void* const* d_in, const int* in_sizes, int n_in,
                              void* d_out, int out_size, void* d_ws, size_t ws_size,
                              hipStream_t stream) {
    const float* xf = (const float*)d_in[0];   // [8192,1024] fp32
    const float* wp = (const float*)d_in[1];   // [1] fp32
    // d_in[2] is W_tile = kron(ones(1,8), eye(1024)): output is 8 tiled
    // copies of the normalized row; no GEMM needed.
    float* out = (float*)d_out;                // [8192, 8192] fp32
    float* ws  = (float*)d_ws;                 // partial sums (<= 1024 floats)

    void* args[] = {(void*)&xf, (void*)&wp, (void*)&ws, (void*)&out};
    hipError_t err = hipLaunchCooperativeKernel(
        (const void*)fused_kernel, dim3(NBLK), dim3(256), args, 0, stream);
    if (err != hipSuccess) {
        // Cooperative launch unavailable (e.g. under capture on older ROCm):
        // fall back to the verified two-kernel path.
        partial_sum_kernel<<<NPART, 1024, 0, stream>>>(xf, ws);
        norm_tile_kernel<<<BATCH / 4, 256, 0, stream>>>(xf, wp, ws, out);
    }
}

// Round 3
// 303.333 us; speedup vs baseline: 1.3065x; 1.3065x over previous
//
#include <hip/hip_runtime.h>
#include <math.h>

// Problem constants (match reference)
#define BATCH 8192
#define DIM   1024
#define GRP   8
#define NPART 256                         // number of partial sums in ws
constexpr float EPS   = 1e-12f;
constexpr float INV_N = 1.0f / (float(BATCH) * float(DIM)); // 1 / 8388608

typedef float floatx4 __attribute__((ext_vector_type(4)));  // native vec for nt-store

// ---------------------------------------------------------------------------
// Kernel A: partial sums of xf -> ws[0..255]. 256 blocks x 1024 threads,
// each thread sums 8 float4s (fully unrolled), block reduce, one store.
// All 256 slots are overwritten, so no zero-init of ws is needed.
// ---------------------------------------------------------------------------
__global__ __launch_bounds__(1024)
void partial_sum_kernel(const float* __restrict__ xf,
                        float* __restrict__ ws) {
    const int tid = threadIdx.x;
    const int gid = blockIdx.x * 1024 + tid;           // 0 .. 262143
    const float4* x4 = reinterpret_cast<const float4*>(xf);
    // total float4 = 2097152 ; stride between a thread's loads = 262144
    float s = 0.0f;
    #pragma unroll
    for (int i = 0; i < 8; ++i) {
        float4 v = x4[gid + i * 262144];
        s += (v.x + v.y) + (v.z + v.w);
    }
    #pragma unroll
    for (int off = 32; off > 0; off >>= 1)
        s += __shfl_down(s, off, 64);

    __shared__ float sm[16];                           // 1024 threads = 16 waves
    const int lane = tid & 63;
    const int wave = tid >> 6;
    if (lane == 0) sm[wave] = s;
    __syncthreads();
    if (tid == 0) {
        float t = 0.0f;
        #pragma unroll
        for (int w = 0; w < 16; ++w) t += sm[w];
        ws[blockIdx.x] = t;
    }
}

// ---------------------------------------------------------------------------
// Kernel B: per-row relu(x-mean), L2 normalize, scale by sigmoid(wp),
// write G=8 tiled copies with nontemporal float4 stores.
// One 256-thread block per row. Reduces the 256 partials itself (L2-hit).
//
// NOTE (rounds 1-2 post-mortem): a wave-per-row zero-LDS variant (304.7 us)
// and a fully-fused cooperative variant (396.3 us) both failed to beat this
// structure (301.5 us). The timed region is dominated by fixed harness cost;
// this kernel's portion is within ~15-20% of the mandatory-traffic roofline
// and insensitive to store-path restructuring. Keep this version.
// ---------------------------------------------------------------------------
__global__ __launch_bounds__(256)
void norm_tile_kernel(const float* __restrict__ xf,
                      const float* __restrict__ wp,
                      const float* __restrict__ ws,
                      float* __restrict__ out) {
    const int row = blockIdx.x;
    const int tid = threadIdx.x;                       // 0..255

    // Issue the row load early so it overlaps the partial-sum reduction.
    const float4* xr = reinterpret_cast<const float4*>(xf + (size_t)row * DIM);
    float4 v = xr[tid];

    // Reduce the 256 partial sums -> global mean.
    float p = ws[tid];
    #pragma unroll
    for (int off = 32; off > 0; off >>= 1)
        p += __shfl_down(p, off, 64);

    __shared__ float sm[4];
    __shared__ float red[2];
    const int lane = tid & 63;
    const int wave = tid >> 6;
    if (lane == 0) sm[wave] = p;
    __syncthreads();
    if (tid == 0) red[0] = (sm[0] + sm[1]) + (sm[2] + sm[3]);
    __syncthreads();
    const float mean = red[0] * INV_N;

    // ReLU(x - mean) and row sum of squares.
    v.x = fmaxf(v.x - mean, 0.0f);
    v.y = fmaxf(v.y - mean, 0.0f);
    v.z = fmaxf(v.z - mean, 0.0f);
    v.w = fmaxf(v.w - mean, 0.0f);

    float s = v.x * v.x + v.y * v.y + v.z * v.z + v.w * v.w;
    #pragma unroll
    for (int off = 32; off > 0; off >>= 1)
        s += __shfl_down(s, off, 64);
    if (lane == 0) sm[wave] = s;                       // safe: after barrier above
    __syncthreads();
    if (tid == 0) red[1] = (sm[0] + sm[1]) + (sm[2] + sm[3]);
    __syncthreads();

    const float norm  = fmaxf(sqrtf(red[1]), EPS);
    const float sig   = 1.0f / (1.0f + expf(-wp[0]));
    const float scale = sig / norm;

    floatx4 o;
    o.x = v.x * scale;
    o.y = v.y * scale;
    o.z = v.z * scale;
    o.w = v.w * scale;

    // 8 tiled copies, nontemporal streaming stores (no reuse of out).
    floatx4* orow = reinterpret_cast<floatx4*>(out + (size_t)row * (GRP * DIM));
    #pragma unroll
    for (int g = 0; g < GRP; ++g)
        __builtin_nontemporal_store(o, &orow[g * (DIM / 4) + tid]);
}

// ---------------------------------------------------------------------------
extern "C" void kernel_launch(void* const* d_in, const int* in_sizes, int n_in,
                              void* d_out, int out_size, void* d_ws, size_t ws_size,
                              hipStream_t stream) {
    const float* xf = (const float*)d_in[0];   // [8192,1024] fp32
    const float* wp = (const float*)d_in[1];   // [1] fp32
    // d_in[2] is W_tile = kron(ones(1,8), eye(1024)) -> output is 8 tiled
    // copies of the normalized row; no GEMM needed.
    float* out = (float*)d_out;                // [8192, 8192] fp32
    float* ws  = (float*)d_ws;                 // ws[0..255] partial sums

    partial_sum_kernel<<<NPART, 1024, 0, stream>>>(xf, ws);
    norm_tile_kernel<<<BATCH, 256, 0, stream>>>(xf, wp, ws, out);
}